// Round 10
// baseline (245.889 us; speedup 1.0000x reference)
//
#include <hip/hip_runtime.h>
#include <math.h>

#define NCAPS 8
#define DD    16
#define D     128
#define M     32
#define ROUTIT 6
#define CUT   5

__device__ __forceinline__ float wred16_sum(float v) {
    v += __shfl_xor(v, 1);
    v += __shfl_xor(v, 2);
    v += __shfl_xor(v, 4);
    v += __shfl_xor(v, 8);
    return v;
}

// per-wave "sync": each routing wave owns a private LDS quarter, so only
// within-wave LDS write->read ordering is needed. lgkmcnt is per-wave.
__device__ __forceinline__ void wave_sync_lds() {
    asm volatile("s_waitcnt lgkmcnt(0)" ::: "memory");
}

// multi-wave barrier WITHOUT the compiler's vmcnt(0) drain: drains own LDS
// ops (lgkmcnt) for cross-wave store visibility, then raw s_barrier. Global
// prefetch loads stay in flight across it (counted vmcnt at the use).
__device__ __forceinline__ void bar_lgkm() {
    asm volatile("s_waitcnt lgkmcnt(0)" ::: "memory");
    __builtin_amdgcn_s_barrier();
    asm volatile("" ::: "memory");
}

// ---- f16 pair pack/unpack (RNE via default float->_Float16 conversion)
typedef _Float16 h2 __attribute__((ext_vector_type(2)));
union U32H2 { unsigned u; h2 h; };
__device__ __forceinline__ unsigned pack_h2(float a, float b) {
    U32H2 r; r.h.x = (_Float16)a; r.h.y = (_Float16)b; return r.u;
}
__device__ __forceinline__ h2 ash2(unsigned u) { U32H2 r; r.u = u; return r.h; }

// ---------------------------------------------------------------- fused PCA GEMM + attn loss + xc0
// (R20 structure: bar_lgkm barriers, merged dummy-row init)
__global__ __launch_bounds__(256) void pca_attn(
        const float* __restrict__ x, const float* __restrict__ w,
        const float* __restrict__ bias, const float* __restrict__ ln_g,
        const float* __restrict__ ln_b, const float* __restrict__ w_qs,
        const float* __restrict__ w_ks, unsigned* __restrict__ xc0H,
        unsigned* __restrict__ xc1H, float* __restrict__ partial,
        int n, int nfeat) {
    // union region: phase1 staging (xs2+ws2 = 6.6 KB) / phase3 ks (20.5 KB)
    __shared__ alignas(16) unsigned char uS[20480];
    unsigned (*xs2)[36]  = (unsigned(*)[36])uS;            // [kkp][row]
    unsigned (*ws2)[128] = (unsigned(*)[128])(uS + 1440);  // [kkp][col]
    float (*ks)[8][20]   = (float(*)[8][20])uS;            // [row][kq][c]
    __shared__ alignas(16) float hs[32][132];              // h tile, +4 pad
    __shared__ float wq[256], wk[256];
    __shared__ float red[4];
    const int tid = threadIdx.x;
    const int cg = tid & 31;
    const int rg = tid >> 5;
    const int row0 = blockIdx.x * 32;
    wq[tid] = w_qs[tid];
    wk[tid] = w_ks[tid];
    const float4 bi4 = *(const float4*)&bias[cg * 4];
    // merged init: dummy row n = 0 in both f16 xc buffers
    if (blockIdx.x == 0 && tid < 64) {
        xc0H[(size_t)n * 64 + tid] = 0u;
        xc1H[(size_t)n * 64 + tid] = 0u;
    }

    // ---- phase 1: f16-pair GEMM, 25 tiles of BK=20 (10 kk-pairs)
    const int xr_r = tid / 5, xr_cf = tid % 5;          // x-loader role (tid<160)
    const int wk0 = tid >> 5, wc0 = tid & 31;           // w task 0 (kkp 0..7)
    float4 xr{}, w0a{}, w0b{}, w1a{}, w1b{};

    // preload tile 0
    {
        if (tid < 160) {
            int row = row0 + xr_r;
            xr = (row < n) ? *(const float4*)&x[(size_t)row * nfeat + xr_cf * 4]
                           : make_float4(0.f, 0.f, 0.f, 0.f);
        }
        w0a = *(const float4*)&w[(size_t)(2 * wk0) * 128 + wc0 * 4];
        w0b = *(const float4*)&w[(size_t)(2 * wk0 + 1) * 128 + wc0 * 4];
        if (tid < 64) {
            int kkp = 8 + (tid >> 5);
            w1a = *(const float4*)&w[(size_t)(2 * kkp) * 128 + wc0 * 4];
            w1b = *(const float4*)&w[(size_t)(2 * kkp + 1) * 128 + wc0 * 4];
        }
    }
    float acc[4][4] = {};
    const int ntile = nfeat / 20;   // 25
    for (int t = 0; t < ntile; ++t) {
        bar_lgkm();   // previous tile's readers done (no vmem drain)
        if (tid < 160) {
            xs2[xr_cf * 2 + 0][xr_r] = pack_h2(xr.x, xr.y);
            xs2[xr_cf * 2 + 1][xr_r] = pack_h2(xr.z, xr.w);
        }
        {
            uint4 pw;
            pw.x = pack_h2(w0a.x, w0b.x); pw.y = pack_h2(w0a.y, w0b.y);
            pw.z = pack_h2(w0a.z, w0b.z); pw.w = pack_h2(w0a.w, w0b.w);
            *(uint4*)&ws2[wk0][wc0 * 4] = pw;
        }
        if (tid < 64) {
            int kkp = 8 + (tid >> 5);
            uint4 pw;
            pw.x = pack_h2(w1a.x, w1b.x); pw.y = pack_h2(w1a.y, w1b.y);
            pw.z = pack_h2(w1a.z, w1b.z); pw.w = pack_h2(w1a.w, w1b.w);
            *(uint4*)&ws2[kkp][wc0 * 4] = pw;
        }
        // issue next tile's loads -- stay in flight through barrier + compute
        if (t < ntile - 1) {
            int k0 = (t + 1) * 20;
            if (tid < 160) {
                int row = row0 + xr_r;
                xr = (row < n)
                    ? *(const float4*)&x[(size_t)row * nfeat + k0 + xr_cf * 4]
                    : make_float4(0.f, 0.f, 0.f, 0.f);
            }
            w0a = *(const float4*)&w[(size_t)(k0 + 2 * wk0) * 128 + wc0 * 4];
            w0b = *(const float4*)&w[(size_t)(k0 + 2 * wk0 + 1) * 128 + wc0 * 4];
            if (tid < 64) {
                int kkp = 8 + (tid >> 5);
                w1a = *(const float4*)&w[(size_t)(k0 + 2 * kkp) * 128 + wc0 * 4];
                w1b = *(const float4*)&w[(size_t)(k0 + 2 * kkp + 1) * 128 + wc0 * 4];
            }
        }
        bar_lgkm();   // LDS tile visible to all waves (no vmem drain)
#pragma unroll
        for (int kkp = 0; kkp < 10; ++kkp) {
            uint4 av = *(const uint4*)&xs2[kkp][rg * 4];   // 4 rows (broadcast)
            uint4 bv = *(const uint4*)&ws2[kkp][cg * 4];   // 4 cols
            unsigned aa[4] = {av.x, av.y, av.z, av.w};
            unsigned bb[4] = {bv.x, bv.y, bv.z, bv.w};
#pragma unroll
            for (int i = 0; i < 4; ++i)
#pragma unroll
                for (int j = 0; j < 4; ++j)
                    acc[i][j] = __builtin_amdgcn_fdot2(ash2(aa[i]), ash2(bb[j]),
                                                       acc[i][j], false);
        }
    }
#pragma unroll
    for (int i = 0; i < 4; ++i)
        *(float4*)&hs[rg * 4 + i][cg * 4] =
            make_float4(acc[i][0] + bi4.x, acc[i][1] + bi4.y,
                        acc[i][2] + bi4.z, acc[i][3] + bi4.w);
    bar_lgkm();   // hs ready; staging buffers dead -> ks may reuse

    // ---- phase 2: per-(row, capsule) LN + q/kk matmuls + xc0
    const int r = tid >> 3, kq = tid & 7;
    const int row = row0 + r;
    float hv[16], q[16], kk[16];
    if (row < n) {
#pragma unroll
        for (int i = 0; i < 4; ++i) {
            float4 f = *(const float4*)&hs[r][kq * 16 + i * 4];
            hv[i * 4 + 0] = f.x; hv[i * 4 + 1] = f.y;
            hv[i * 4 + 2] = f.z; hv[i * 4 + 3] = f.w;
        }
        float mu = 0.f;
#pragma unroll
        for (int c = 0; c < 16; ++c) mu += hv[c];
        mu *= (1.f / 16.f);
        float var = 0.f;
#pragma unroll
        for (int c = 0; c < 16; ++c) { float d = hv[c] - mu; var += d * d; }
        var *= (1.f / 16.f);
        float rstd = rsqrtf(var + 1e-6f);
        float qn[16];
#pragma unroll
        for (int c = 0; c < 16; ++c)
            qn[c] = (hv[c] - mu) * rstd * ln_g[c] + ln_b[c];
#pragma unroll
        for (int c = 0; c < 16; ++c) { q[c] = 0.f; kk[c] = 0.f; }
#pragma unroll
        for (int cp = 0; cp < 16; ++cp)
#pragma unroll
            for (int c = 0; c < 16; ++c) {
                q[c]  += qn[cp] * wq[cp * 16 + c];
                kk[c] += hv[cp] * wk[cp * 16 + c];
            }
#pragma unroll
        for (int c = 0; c < 16; ++c) q[c] *= 0.25f;   // 1/sqrt(16)
#pragma unroll
        for (int i = 0; i < 4; ++i)
            *(float4*)&ks[r][kq][i * 4] =
                make_float4(kk[i * 4], kk[i * 4 + 1], kk[i * 4 + 2], kk[i * 4 + 3]);
        float ss = 0.f;
        float rl[16];
#pragma unroll
        for (int c = 0; c < 16; ++c) { rl[c] = fmaxf(hv[c], 0.f); ss += rl[c] * rl[c]; }
        float inv = 1.f / fmaxf(sqrtf(ss), 1e-12f);
        unsigned* xo = xc0H + (size_t)row * 64 + kq * 8;
        uint4 pa, pb;
        pa.x = pack_h2(rl[0] * inv,  rl[1] * inv);
        pa.y = pack_h2(rl[2] * inv,  rl[3] * inv);
        pa.z = pack_h2(rl[4] * inv,  rl[5] * inv);
        pa.w = pack_h2(rl[6] * inv,  rl[7] * inv);
        pb.x = pack_h2(rl[8] * inv,  rl[9] * inv);
        pb.y = pack_h2(rl[10] * inv, rl[11] * inv);
        pb.z = pack_h2(rl[12] * inv, rl[13] * inv);
        pb.w = pack_h2(rl[14] * inv, rl[15] * inv);
        *(uint4*)&xo[0] = pa;
        *(uint4*)&xo[4] = pb;
    }
    bar_lgkm();

    // ---- phase 3: scores row kq vs all 8 keys; softmax; off-diag sum
    float offd = 0.f;
    if (row < n) {
        float s[8];
#pragma unroll
        for (int j = 0; j < 8; ++j) {
            float d = 0.f;
#pragma unroll
            for (int i = 0; i < 4; ++i) {
                float4 f = *(const float4*)&ks[r][j][i * 4];
                d += q[i * 4] * f.x + q[i * 4 + 1] * f.y
                   + q[i * 4 + 2] * f.z + q[i * 4 + 3] * f.w;
            }
            s[j] = d;
        }
        float mx = s[0];
#pragma unroll
        for (int j = 1; j < 8; ++j) mx = fmaxf(mx, s[j]);
        float e[8], se = 0.f;
#pragma unroll
        for (int j = 0; j < 8; ++j) { e[j] = __expf(s[j] - mx); se += e[j]; }
        float rse = 1.f / se;
#pragma unroll
        for (int j = 0; j < 8; ++j)
            if (j != kq) offd += e[j] * rse;
    }
    offd += __shfl_xor(offd, 1);
    offd += __shfl_xor(offd, 2);
    offd += __shfl_xor(offd, 4);
    offd += __shfl_xor(offd, 8);
    offd += __shfl_xor(offd, 16);
    offd += __shfl_xor(offd, 32);
    int lane = tid & 63, wid = tid >> 6;
    if (lane == 0) red[wid] = offd;
    bar_lgkm();
    if (tid == 0) partial[blockIdx.x] = red[0] + red[1] + red[2] + red[3];
}

// ---------------------------------------------------------------- routing: 4 NODES PER 256-THREAD BLOCK
// R22: identical per-wave code, but 4 independent waves (4 nodes) share one
// workgroup. Each wave owns a private 8 KB LDS quarter; all syncs remain
// per-wave lgkmcnt drains (no cross-wave coupling). Grid 20000 -> 5000:
// better dispatch granularity toward the 16-wave/CU register cap.
// usu/pT alias zsu rows 26..31 so rows 0..4 survive for the merged s2.
template <bool LAST>
__global__ __launch_bounds__(256, 4) void routing_kernel(
        const unsigned* __restrict__ xcH, // (n+1)*64 f16-pairs, row n = 0
        const int* __restrict__ nb,       // n*32
        float* __restrict__ outF,         // LAST: u1 rows [0,n)
        unsigned* __restrict__ outH,      // !LAST: xc_next f16 rows [0,n)
        int* __restrict__ amax,           // LAST: n*32 argmax
        float* __restrict__ s2out,        // LAST: n*16 second-hop presum
        int n) {
    __shared__ alignas(16) unsigned char sbuf4[4][8192];
    const int wid = threadIdx.x >> 6;
    const int l = threadIdx.x & 63;
    const int v = blockIdx.x * 4 + wid;
    if (v >= n) return;   // n % 4 == 0 in practice; safety only
    unsigned char* sbuf = sbuf4[wid];
    uint2* zsu = (uint2*)sbuf;            // [M*32] f16x4 staging slots
    uint2* usu = (uint2*)(sbuf + 6656);   // [40]   aliases zsu rows 26..27
    float* pT  = (float*)(sbuf + 6976);   // [8*36] aliases zsu rows ~27..31
    const int m  = l & 31;   // also f4 (dd-slot index in update phase)
    const int kh = l >> 5;   // also mg (row-half index in update phase)

    // ---- stage 32 neighbor rows -> LDS (XOR-swizzled slots), f16 direct
    float4 x3;
    {
        int sm = l >> 1, sh = l & 1;
        int src = 0;
        if (l < M) {
            int nbv = nb[(size_t)v * M + l];
            src = (nbv < 0) ? n : nbv;
        }
        int srow = __shfl(src, sm);
        const uint4* g = (const uint4*)(xcH + (size_t)srow * 64 + sh * 32);
        uint2 xv = *(const uint2*)(xcH + (size_t)v * 64 + m * 2);
        uint4 zb[8];
#pragma unroll
        for (int i = 0; i < 8; ++i) zb[i] = g[i];      // all 8 loads in flight
        {
            h2 xlo = ash2(xv.x), xhi = ash2(xv.y);
            x3 = make_float4((float)xlo.x, (float)xlo.y,
                             (float)xhi.x, (float)xhi.y);
        }
#pragma unroll
        for (int i = 0; i < 8; ++i) {
            int f0 = sh * 16 + 2 * i;
            zsu[sm * 32 + (f0 ^ sm)]       = make_uint2(zb[i].x, zb[i].y);
            zsu[sm * 32 + ((f0 + 1) ^ sm)] = make_uint2(zb[i].z, zb[i].w);
        }
    }
    wave_sync_lds();

    // ---- one-time register hoist of both z access patterns (forced: the
    // usu/pT writes below may alias zsu, so these cannot be rematerialized)
    uint2 zpr[16];
#pragma unroll
    for (int idx = 0; idx < 16; ++idx) {
        int f = kh * 16 + idx;
        zpr[idx] = zsu[m * 32 + (f ^ m)];
    }
    uint2 zu[16];
#pragma unroll
    for (int j = 0; j < 16; ++j) {
        int r = kh * 16 + j;
        zu[j] = zsu[r * 32 + (m ^ r)];
    }
    wave_sync_lds();   // all hoist reads done before usu/pT clobber rows 26..31

    // ---- initial u: mean over 32 neighbor rows (p = 1/8 uniform) + x3
    {
        float4 a = make_float4(0.f, 0.f, 0.f, 0.f);
#pragma unroll
        for (int j = 0; j < 16; ++j) {
            h2 lo = ash2(zu[j].x), hi = ash2(zu[j].y);
            a.x += (float)lo.x; a.y += (float)lo.y;
            a.z += (float)hi.x; a.w += (float)hi.y;
        }
        a.x += __shfl_xor(a.x, 32); a.y += __shfl_xor(a.y, 32);
        a.z += __shfl_xor(a.z, 32); a.w += __shfl_xor(a.w, 32);
        a.x = a.x * 0.125f + x3.x;  a.y = a.y * 0.125f + x3.y;
        a.z = a.z * 0.125f + x3.z;  a.w = a.w * 0.125f + x3.w;
        float ss = a.x * a.x + a.y * a.y + a.z * a.z + a.w * a.w;
        ss += __shfl_xor(ss, 1); ss += __shfl_xor(ss, 2);
        float inv = 1.f / fmaxf(sqrtf(ss), 1e-12f);
        if (l < 32)
            usu[(m >> 2) * 5 + (m & 3)] =
                make_uint2(pack_h2(a.x * inv, a.y * inv),
                           pack_h2(a.z * inv, a.w * inv));
    }
    wave_sync_lds();

    int my_amax = 0;
    for (int it = 1; it < ROUTIT; ++it) {
        // ---- p = z . u  (z from registers, u broadcast from LDS)
        float pr[4];
#pragma unroll
        for (int j = 0; j < 4; ++j) {
            float s = 0.f;
            const uint2* uk = &usu[(kh * 4 + j) * 5];
#pragma unroll
            for (int c2 = 0; c2 < 4; ++c2) {
                uint2 zz = zpr[j * 4 + c2];
                uint2 uu = uk[c2];
                s = __builtin_amdgcn_fdot2(ash2(zz.x), ash2(uu.x), s, false);
                s = __builtin_amdgcn_fdot2(ash2(zz.y), ash2(uu.y), s, false);
            }
            pr[j] = s;
        }
        float po[4];
#pragma unroll
        for (int j = 0; j < 4; ++j) po[j] = __shfl_xor(pr[j], 32);
        if (LAST && it == ROUTIT - 1) {
            float p8[8];
#pragma unroll
            for (int j = 0; j < 4; ++j) {
                p8[kh * 4 + j] = pr[j];
                p8[(kh ^ 1) * 4 + j] = po[j];
            }
            float bv = p8[0]; int bi = 0;
#pragma unroll
            for (int k2 = 1; k2 < 8; ++k2)
                if (p8[k2] > bv) { bv = p8[k2]; bi = k2; }
            my_amax = bi;
            if (l < 32) amax[(size_t)v * M + m] = bi;
        }
        float er[4], S = 0.f;
#pragma unroll
        for (int j = 0; j < 4; ++j) { er[j] = __expf(pr[j]); S += er[j]; }
#pragma unroll
        for (int j = 0; j < 4; ++j) S += __expf(po[j]);
        float rS = 1.f / S;
#pragma unroll
        for (int j = 0; j < 4; ++j)
            pT[(kh * 4 + j) * 36 + m] = er[j] * rS;
        wave_sync_lds();

        // ---- gather p for this lane's (capsule, row-half)
        float pk[16];
        {
            const int k2 = m >> 2;
#pragma unroll
            for (int j4 = 0; j4 < 4; ++j4) {
                float4 pp = *(const float4*)&pT[k2 * 36 + kh * 16 + j4 * 4];
                pk[j4 * 4 + 0] = pp.x; pk[j4 * 4 + 1] = pp.y;
                pk[j4 * 4 + 2] = pp.z; pk[j4 * 4 + 3] = pp.w;
            }
        }
        // ---- u update: a = sum_j z[row j][slot m] * p  (z from registers)
        float4 a = make_float4(0.f, 0.f, 0.f, 0.f);
#pragma unroll
        for (int j = 0; j < 16; ++j) {
            h2 lo = ash2(zu[j].x), hi = ash2(zu[j].y);
            a.x += (float)lo.x * pk[j]; a.y += (float)lo.y * pk[j];
            a.z += (float)hi.x * pk[j]; a.w += (float)hi.y * pk[j];
        }
        a.x += __shfl_xor(a.x, 32); a.y += __shfl_xor(a.y, 32);
        a.z += __shfl_xor(a.z, 32); a.w += __shfl_xor(a.w, 32);
        a.x += x3.x; a.y += x3.y; a.z += x3.z; a.w += x3.w;

        if (it < ROUTIT - 1) {
            float ss = a.x * a.x + a.y * a.y + a.z * a.z + a.w * a.w;
            ss += __shfl_xor(ss, 1); ss += __shfl_xor(ss, 2);
            float inv = 1.f / fmaxf(sqrtf(ss), 1e-12f);
            if (l < 32)
                usu[(m >> 2) * 5 + (m & 3)] =
                    make_uint2(pack_h2(a.x * inv, a.y * inv),
                               pack_h2(a.z * inv, a.w * inv));
            wave_sync_lds();
        } else if (LAST) {
            if (l < 32) ((float4*)(outF + (size_t)v * D))[m] = a;
            // ---- merged s2: sum first-5-neighbor selected capsules from
            // intact zsu rows 0..4 (z == those nodes' xc1 rows, row n = 0)
            int c = l & 15;
            float s = 0.f;
#pragma unroll
            for (int b = 0; b < CUT; ++b) {
                int jjb = __shfl(my_amax, b);        // argmax of row b (lane b)
                int slot = jjb * 4 + (c >> 2);
                uint2 zz = zsu[b * 32 + (slot ^ b)];
                unsigned word = (c & 2) ? zz.y : zz.x;
                h2 hh = ash2(word);
                s += (c & 1) ? (float)hh.y : (float)hh.x;
            }
            if (l < 16) s2out[(size_t)v * 16 + c] = s;
        } else {
            float r0 = fmaxf(a.x, 0.f), r1 = fmaxf(a.y, 0.f);
            float r2 = fmaxf(a.z, 0.f), r3 = fmaxf(a.w, 0.f);
            float ss = r0 * r0 + r1 * r1 + r2 * r2 + r3 * r3;
            ss += __shfl_xor(ss, 1); ss += __shfl_xor(ss, 2);
            float inv = 1.f / fmaxf(sqrtf(ss), 1e-12f);
            if (l < 32)
                *(uint2*)(outH + (size_t)v * 64 + m * 2) =
                    make_uint2(pack_h2(r0 * inv, r1 * inv),
                               pack_h2(r2 * inv, r3 * inv));
        }
    }
}

// ---------------------------------------------------------------- meta gather + MLP + log_softmax
// (R21: attn-loss partial sum merged in, block 0 wave 0)
__global__ __launch_bounds__(256) void meta_kernel(
        const float* __restrict__ u1, const float* __restrict__ s2,
        const int* __restrict__ nb, const int* __restrict__ amax,
        const float* __restrict__ mlp_w, const float* __restrict__ mlp_b,
        const float* __restrict__ partial, float* __restrict__ d_out,
        int n, int npart) {
    __shared__ float Wl[128 * 16];
    __shared__ float accs[16][132];
    const int t = threadIdx.x;
#pragma unroll
    for (int i = 0; i < 8; ++i) Wl[t + i * 256] = mlp_w[t + i * 256];
    const int g = t >> 4, c = t & 15;
    const int v = blockIdx.x * 16 + g;
    if (blockIdx.x == 0 && t < 64) {
        float s = 0.f;
        for (int i = t; i < npart; i += 64) s += partial[i];
        s += __shfl_xor(s, 1);  s += __shfl_xor(s, 2);
        s += __shfl_xor(s, 4);  s += __shfl_xor(s, 8);
        s += __shfl_xor(s, 16); s += __shfl_xor(s, 32);
        if (t == 0) d_out[(size_t)n * 16] = s * (1.f / (56.f * (float)n));
    }
    if (v < n) {
#pragma unroll
        for (int i = 0; i < 8; ++i) accs[g][i * 16 + c] = 0.f;
        for (int a = 0; a < CUT; ++a) {
            int w = nb[(size_t)v * M + a];
            if (w < 0) continue;
            int i = amax[(size_t)v * M + a];   // first-hop capsule
            accs[g][i * 16 + c] += s2[(size_t)w * 16 + c];
        }
#pragma unroll
        for (int i = 0; i < 8; ++i) {
            float meta = u1[(size_t)v * D + i * 16 + c] + accs[g][i * 16 + c] * (1.f / 25.f);
            accs[g][i * 16 + c] = fmaxf(meta, 0.f);
        }
    }
    __syncthreads();
    if (v < n) {
        float o = mlp_b[c];
#pragma unroll
        for (int dd = 0; dd < 128; ++dd) o += accs[g][dd] * Wl[dd * 16 + c];
        float mx = o;
        mx = fmaxf(mx, __shfl_xor(mx, 1));
        mx = fmaxf(mx, __shfl_xor(mx, 2));
        mx = fmaxf(mx, __shfl_xor(mx, 4));
        mx = fmaxf(mx, __shfl_xor(mx, 8));
        float e = __expf(o - mx);
        float se = wred16_sum(e);
        float ls = (o - mx) - logf(se);
        d_out[(size_t)v * 16 + c] = ls;
        d_out[(size_t)n * 16 + 1 + (size_t)v * 16 + c] = o;
    }
}

// ---------------------------------------------------------------- launch
extern "C" void kernel_launch(void* const* d_in, const int* in_sizes, int n_in,
                              void* d_out, int out_size, void* d_ws, size_t ws_size,
                              hipStream_t stream) {
    const float* x     = (const float*)d_in[0];
    const int*   nb    = (const int*)d_in[1];
    const float* pca_w = (const float*)d_in[2];
    const float* pca_b = (const float*)d_in[3];
    const float* ln_g  = (const float*)d_in[4];
    const float* ln_b  = (const float*)d_in[5];
    const float* w_qs  = (const float*)d_in[6];
    const float* w_ks  = (const float*)d_in[7];
    const float* mlp_w = (const float*)d_in[8];
    const float* mlp_b = (const float*)d_in[9];
    float* out = (float*)d_out;

    const int d = 128;
    const int nfeat = in_sizes[2] / d;      // 500
    const int n = in_sizes[0] / nfeat;      // 20000
    const int nblk = (n + 31) / 32;         // fused pca_attn blocks (625)

    float* bufA = (float*)d_ws;                           // n*128 f32 : u1
    unsigned* bufB = (unsigned*)(bufA + (size_t)n * d);   // (n+1)*64 : xc0 f16; later amax+s2
    unsigned* bufC = bufB + (size_t)(n + 1) * 64;         // (n+1)*64 : xc1 f16
    float* partial = (float*)(bufC + (size_t)(n + 1) * 64);  // nblk floats, dedicated
    int* amax = (int*)bufB;                               // n*32 ints (xc0 dead)
    float* s2 = (float*)((int*)bufB + (size_t)n * M);     // n*16 floats, after amax

    pca_attn<<<nblk, 256, 0, stream>>>(x, pca_w, pca_b, ln_g, ln_b, w_qs, w_ks,
                                       bufB, bufC, partial, n, nfeat);
    routing_kernel<false><<<(n + 3) / 4, 256, 0, stream>>>(bufB, nb, nullptr, bufC,
                                                           nullptr, nullptr, n);
    routing_kernel<true><<<(n + 3) / 4, 256, 0, stream>>>(bufC, nb, bufA, nullptr,
                                                          amax, s2, n);
    meta_kernel<<<(n + 15) / 16, 256, 0, stream>>>(bufA, s2, nb, amax, mlp_w,
                                                   mlp_b, partial, out, n, nblk);
}

// Round 11
// 245.386 us; speedup vs baseline: 1.0021x; 1.0021x over previous
//
#include <hip/hip_runtime.h>
#include <math.h>

#define NCAPS 8
#define DD    16
#define D     128
#define M     32
#define ROUTIT 6
#define CUT   5

__device__ __forceinline__ float wred16_sum(float v) {
    v += __shfl_xor(v, 1);
    v += __shfl_xor(v, 2);
    v += __shfl_xor(v, 4);
    v += __shfl_xor(v, 8);
    return v;
}

// per-wave "sync" (1-wave routing blocks): only LDS ordering needed.
__device__ __forceinline__ void wave_sync_lds() {
    asm volatile("s_waitcnt lgkmcnt(0)" ::: "memory");
}

// multi-wave barrier WITHOUT the compiler's vmcnt(0) drain.
__device__ __forceinline__ void bar_lgkm() {
    asm volatile("s_waitcnt lgkmcnt(0)" ::: "memory");
    __builtin_amdgcn_s_barrier();
    asm volatile("" ::: "memory");
}

// ---- f16 pair pack/unpack (RNE via default float->_Float16 conversion)
typedef _Float16 h2 __attribute__((ext_vector_type(2)));
union U32H2 { unsigned u; h2 h; };
__device__ __forceinline__ unsigned pack_h2(float a, float b) {
    U32H2 r; r.h.x = (_Float16)a; r.h.y = (_Float16)b; return r.u;
}
__device__ __forceinline__ h2 ash2(unsigned u) { U32H2 r; r.u = u; return r.h; }

// ---------------------------------------------------------------- fused PCA GEMM + attn loss + xc0
// (R20 structure: bar_lgkm barriers, merged dummy-row init)
__global__ __launch_bounds__(256) void pca_attn(
        const float* __restrict__ x, const float* __restrict__ w,
        const float* __restrict__ bias, const float* __restrict__ ln_g,
        const float* __restrict__ ln_b, const float* __restrict__ w_qs,
        const float* __restrict__ w_ks, unsigned* __restrict__ xc0H,
        unsigned* __restrict__ xc1H, float* __restrict__ partial,
        int n, int nfeat) {
    // union region: phase1 staging (xs2+ws2 = 6.6 KB) / phase3 ks (20.5 KB)
    __shared__ alignas(16) unsigned char uS[20480];
    unsigned (*xs2)[36]  = (unsigned(*)[36])uS;            // [kkp][row]
    unsigned (*ws2)[128] = (unsigned(*)[128])(uS + 1440);  // [kkp][col]
    float (*ks)[8][20]   = (float(*)[8][20])uS;            // [row][kq][c]
    __shared__ alignas(16) float hs[32][132];              // h tile, +4 pad
    __shared__ float wq[256], wk[256];
    __shared__ float red[4];
    const int tid = threadIdx.x;
    const int cg = tid & 31;
    const int rg = tid >> 5;
    const int row0 = blockIdx.x * 32;
    wq[tid] = w_qs[tid];
    wk[tid] = w_ks[tid];
    const float4 bi4 = *(const float4*)&bias[cg * 4];
    // merged init: dummy row n = 0 in both f16 xc buffers
    if (blockIdx.x == 0 && tid < 64) {
        xc0H[(size_t)n * 64 + tid] = 0u;
        xc1H[(size_t)n * 64 + tid] = 0u;
    }

    // ---- phase 1: f16-pair GEMM, 25 tiles of BK=20 (10 kk-pairs)
    const int xr_r = tid / 5, xr_cf = tid % 5;          // x-loader role (tid<160)
    const int wk0 = tid >> 5, wc0 = tid & 31;           // w task 0 (kkp 0..7)
    float4 xr{}, w0a{}, w0b{}, w1a{}, w1b{};

    // preload tile 0
    {
        if (tid < 160) {
            int row = row0 + xr_r;
            xr = (row < n) ? *(const float4*)&x[(size_t)row * nfeat + xr_cf * 4]
                           : make_float4(0.f, 0.f, 0.f, 0.f);
        }
        w0a = *(const float4*)&w[(size_t)(2 * wk0) * 128 + wc0 * 4];
        w0b = *(const float4*)&w[(size_t)(2 * wk0 + 1) * 128 + wc0 * 4];
        if (tid < 64) {
            int kkp = 8 + (tid >> 5);
            w1a = *(const float4*)&w[(size_t)(2 * kkp) * 128 + wc0 * 4];
            w1b = *(const float4*)&w[(size_t)(2 * kkp + 1) * 128 + wc0 * 4];
        }
    }
    float acc[4][4] = {};
    const int ntile = nfeat / 20;   // 25
    for (int t = 0; t < ntile; ++t) {
        bar_lgkm();   // previous tile's readers done (no vmem drain)
        if (tid < 160) {
            xs2[xr_cf * 2 + 0][xr_r] = pack_h2(xr.x, xr.y);
            xs2[xr_cf * 2 + 1][xr_r] = pack_h2(xr.z, xr.w);
        }
        {
            uint4 pw;
            pw.x = pack_h2(w0a.x, w0b.x); pw.y = pack_h2(w0a.y, w0b.y);
            pw.z = pack_h2(w0a.z, w0b.z); pw.w = pack_h2(w0a.w, w0b.w);
            *(uint4*)&ws2[wk0][wc0 * 4] = pw;
        }
        if (tid < 64) {
            int kkp = 8 + (tid >> 5);
            uint4 pw;
            pw.x = pack_h2(w1a.x, w1b.x); pw.y = pack_h2(w1a.y, w1b.y);
            pw.z = pack_h2(w1a.z, w1b.z); pw.w = pack_h2(w1a.w, w1b.w);
            *(uint4*)&ws2[kkp][wc0 * 4] = pw;
        }
        // issue next tile's loads -- stay in flight through barrier + compute
        if (t < ntile - 1) {
            int k0 = (t + 1) * 20;
            if (tid < 160) {
                int row = row0 + xr_r;
                xr = (row < n)
                    ? *(const float4*)&x[(size_t)row * nfeat + k0 + xr_cf * 4]
                    : make_float4(0.f, 0.f, 0.f, 0.f);
            }
            w0a = *(const float4*)&w[(size_t)(k0 + 2 * wk0) * 128 + wc0 * 4];
            w0b = *(const float4*)&w[(size_t)(k0 + 2 * wk0 + 1) * 128 + wc0 * 4];
            if (tid < 64) {
                int kkp = 8 + (tid >> 5);
                w1a = *(const float4*)&w[(size_t)(k0 + 2 * kkp) * 128 + wc0 * 4];
                w1b = *(const float4*)&w[(size_t)(k0 + 2 * kkp + 1) * 128 + wc0 * 4];
            }
        }
        bar_lgkm();   // LDS tile visible to all waves (no vmem drain)
#pragma unroll
        for (int kkp = 0; kkp < 10; ++kkp) {
            uint4 av = *(const uint4*)&xs2[kkp][rg * 4];   // 4 rows (broadcast)
            uint4 bv = *(const uint4*)&ws2[kkp][cg * 4];   // 4 cols
            unsigned aa[4] = {av.x, av.y, av.z, av.w};
            unsigned bb[4] = {bv.x, bv.y, bv.z, bv.w};
#pragma unroll
            for (int i = 0; i < 4; ++i)
#pragma unroll
                for (int j = 0; j < 4; ++j)
                    acc[i][j] = __builtin_amdgcn_fdot2(ash2(aa[i]), ash2(bb[j]),
                                                       acc[i][j], false);
        }
    }
#pragma unroll
    for (int i = 0; i < 4; ++i)
        *(float4*)&hs[rg * 4 + i][cg * 4] =
            make_float4(acc[i][0] + bi4.x, acc[i][1] + bi4.y,
                        acc[i][2] + bi4.z, acc[i][3] + bi4.w);
    bar_lgkm();   // hs ready; staging buffers dead -> ks may reuse

    // ---- phase 2: per-(row, capsule) LN + q/kk matmuls + xc0
    const int r = tid >> 3, kq = tid & 7;
    const int row = row0 + r;
    float hv[16], q[16], kk[16];
    if (row < n) {
#pragma unroll
        for (int i = 0; i < 4; ++i) {
            float4 f = *(const float4*)&hs[r][kq * 16 + i * 4];
            hv[i * 4 + 0] = f.x; hv[i * 4 + 1] = f.y;
            hv[i * 4 + 2] = f.z; hv[i * 4 + 3] = f.w;
        }
        float mu = 0.f;
#pragma unroll
        for (int c = 0; c < 16; ++c) mu += hv[c];
        mu *= (1.f / 16.f);
        float var = 0.f;
#pragma unroll
        for (int c = 0; c < 16; ++c) { float d = hv[c] - mu; var += d * d; }
        var *= (1.f / 16.f);
        float rstd = rsqrtf(var + 1e-6f);
        float qn[16];
#pragma unroll
        for (int c = 0; c < 16; ++c)
            qn[c] = (hv[c] - mu) * rstd * ln_g[c] + ln_b[c];
#pragma unroll
        for (int c = 0; c < 16; ++c) { q[c] = 0.f; kk[c] = 0.f; }
#pragma unroll
        for (int cp = 0; cp < 16; ++cp)
#pragma unroll
            for (int c = 0; c < 16; ++c) {
                q[c]  += qn[cp] * wq[cp * 16 + c];
                kk[c] += hv[cp] * wk[cp * 16 + c];
            }
#pragma unroll
        for (int c = 0; c < 16; ++c) q[c] *= 0.25f;   // 1/sqrt(16)
#pragma unroll
        for (int i = 0; i < 4; ++i)
            *(float4*)&ks[r][kq][i * 4] =
                make_float4(kk[i * 4], kk[i * 4 + 1], kk[i * 4 + 2], kk[i * 4 + 3]);
        float ss = 0.f;
        float rl[16];
#pragma unroll
        for (int c = 0; c < 16; ++c) { rl[c] = fmaxf(hv[c], 0.f); ss += rl[c] * rl[c]; }
        float inv = 1.f / fmaxf(sqrtf(ss), 1e-12f);
        unsigned* xo = xc0H + (size_t)row * 64 + kq * 8;
        uint4 pa, pb;
        pa.x = pack_h2(rl[0] * inv,  rl[1] * inv);
        pa.y = pack_h2(rl[2] * inv,  rl[3] * inv);
        pa.z = pack_h2(rl[4] * inv,  rl[5] * inv);
        pa.w = pack_h2(rl[6] * inv,  rl[7] * inv);
        pb.x = pack_h2(rl[8] * inv,  rl[9] * inv);
        pb.y = pack_h2(rl[10] * inv, rl[11] * inv);
        pb.z = pack_h2(rl[12] * inv, rl[13] * inv);
        pb.w = pack_h2(rl[14] * inv, rl[15] * inv);
        *(uint4*)&xo[0] = pa;
        *(uint4*)&xo[4] = pb;
    }
    bar_lgkm();

    // ---- phase 3: scores row kq vs all 8 keys; softmax; off-diag sum
    float offd = 0.f;
    if (row < n) {
        float s[8];
#pragma unroll
        for (int j = 0; j < 8; ++j) {
            float d = 0.f;
#pragma unroll
            for (int i = 0; i < 4; ++i) {
                float4 f = *(const float4*)&ks[r][j][i * 4];
                d += q[i * 4] * f.x + q[i * 4 + 1] * f.y
                   + q[i * 4 + 2] * f.z + q[i * 4 + 3] * f.w;
            }
            s[j] = d;
        }
        float mx = s[0];
#pragma unroll
        for (int j = 1; j < 8; ++j) mx = fmaxf(mx, s[j]);
        float e[8], se = 0.f;
#pragma unroll
        for (int j = 0; j < 8; ++j) { e[j] = __expf(s[j] - mx); se += e[j]; }
        float rse = 1.f / se;
#pragma unroll
        for (int j = 0; j < 8; ++j)
            if (j != kq) offd += e[j] * rse;
    }
    offd += __shfl_xor(offd, 1);
    offd += __shfl_xor(offd, 2);
    offd += __shfl_xor(offd, 4);
    offd += __shfl_xor(offd, 8);
    offd += __shfl_xor(offd, 16);
    offd += __shfl_xor(offd, 32);
    int lane = tid & 63, wid = tid >> 6;
    if (lane == 0) red[wid] = offd;
    bar_lgkm();
    if (tid == 0) partial[blockIdx.x] = red[0] + red[1] + red[2] + red[3];
}

// ---------------------------------------------------------------- routing: ONE WAVE PER NODE
// R23 = R21 structure (1 wave/block; R22's 4-pack regressed, reverted) with
// VALU-count reduction via the fdot2 identity dot2((a,b),(p,0)) = a*p:
//  - init-u: fdot2 with constant (1,0)/(0,1) h2 -> kills 128 v_cvt_f32_f16
//  - pT stores (pk,0),(0,pk) f16 pairs (packed once by producer); u-update
//    becomes 64 pure v_dot2_f32_f16 (no cvt, no mul). pk f16-rounding adds
//    ~2^-11 relative -- negligible vs existing f16 z quantization.
//  - softmax denominator: shfl exp(pr) instead of re-exp'ing shfl'd logits
//    (bit-identical, saves 4 v_exp/iter). pr-shfl kept in the amax branch.
// usu/pT2 alias zsu bytes 5568..8192 (rows ~22..31); rows 0..4 survive for
// the merged s2 epilogue; aliasing still blocks z rematerialization.
template <bool LAST>
__global__ __launch_bounds__(64, 4) void routing_kernel(
        const unsigned* __restrict__ xcH, // (n+1)*64 f16-pairs, row n = 0
        const int* __restrict__ nb,       // n*32
        float* __restrict__ outF,         // LAST: u1 rows [0,n)
        unsigned* __restrict__ outH,      // !LAST: xc_next f16 rows [0,n)
        int* __restrict__ amax,           // LAST: n*32 argmax
        float* __restrict__ s2out,        // LAST: n*16 second-hop presum
        int n) {
    __shared__ alignas(16) unsigned char sbuf[8192];
    uint2* zsu = (uint2*)sbuf;            // [M*32] f16x4 staging slots
    uint2* usu = (uint2*)(sbuf + 5568);   // [40]  aliases zsu rows ~21..22
    uint2* pT2 = (uint2*)(sbuf + 5888);   // [288] aliases zsu rows 23..31
    const int l = threadIdx.x;
    const int v = blockIdx.x;
    const int m  = l & 31;   // also f4 (dd-slot index in update phase)
    const int kh = l >> 5;   // also mg (row-half index in update phase)
    const unsigned ONE_LO = 0x00003C00u;  // h2(1,0)
    const unsigned ONE_HI = 0x3C000000u;  // h2(0,1)

    // ---- stage 32 neighbor rows -> LDS (XOR-swizzled slots), f16 direct
    float4 x3;
    {
        int sm = l >> 1, sh = l & 1;
        int src = 0;
        if (l < M) {
            int nbv = nb[(size_t)v * M + l];
            src = (nbv < 0) ? n : nbv;
        }
        int srow = __shfl(src, sm);
        const uint4* g = (const uint4*)(xcH + (size_t)srow * 64 + sh * 32);
        uint2 xv = *(const uint2*)(xcH + (size_t)v * 64 + m * 2);
        uint4 zb[8];
#pragma unroll
        for (int i = 0; i < 8; ++i) zb[i] = g[i];      // all 8 loads in flight
        {
            h2 xlo = ash2(xv.x), xhi = ash2(xv.y);
            x3 = make_float4((float)xlo.x, (float)xlo.y,
                             (float)xhi.x, (float)xhi.y);
        }
#pragma unroll
        for (int i = 0; i < 8; ++i) {
            int f0 = sh * 16 + 2 * i;
            zsu[sm * 32 + (f0 ^ sm)]       = make_uint2(zb[i].x, zb[i].y);
            zsu[sm * 32 + ((f0 + 1) ^ sm)] = make_uint2(zb[i].z, zb[i].w);
        }
    }
    wave_sync_lds();

    // ---- one-time register hoist of both z access patterns (forced: the
    // usu/pT2 writes below may alias zsu, so these cannot be rematerialized)
    uint2 zpr[16];
#pragma unroll
    for (int idx = 0; idx < 16; ++idx) {
        int f = kh * 16 + idx;
        zpr[idx] = zsu[m * 32 + (f ^ m)];
    }
    uint2 zu[16];
#pragma unroll
    for (int j = 0; j < 16; ++j) {
        int r = kh * 16 + j;
        zu[j] = zsu[r * 32 + (m ^ r)];
    }
    wave_sync_lds();   // all hoist reads done before usu/pT2 clobber rows 22+

    // ---- initial u: mean over 32 neighbor rows (p = 1/8 uniform) + x3
    {
        float4 a = make_float4(0.f, 0.f, 0.f, 0.f);
#pragma unroll
        for (int j = 0; j < 16; ++j) {
            a.x = __builtin_amdgcn_fdot2(ash2(zu[j].x), ash2(ONE_LO), a.x, false);
            a.y = __builtin_amdgcn_fdot2(ash2(zu[j].x), ash2(ONE_HI), a.y, false);
            a.z = __builtin_amdgcn_fdot2(ash2(zu[j].y), ash2(ONE_LO), a.z, false);
            a.w = __builtin_amdgcn_fdot2(ash2(zu[j].y), ash2(ONE_HI), a.w, false);
        }
        a.x += __shfl_xor(a.x, 32); a.y += __shfl_xor(a.y, 32);
        a.z += __shfl_xor(a.z, 32); a.w += __shfl_xor(a.w, 32);
        a.x = a.x * 0.125f + x3.x;  a.y = a.y * 0.125f + x3.y;
        a.z = a.z * 0.125f + x3.z;  a.w = a.w * 0.125f + x3.w;
        float ss = a.x * a.x + a.y * a.y + a.z * a.z + a.w * a.w;
        ss += __shfl_xor(ss, 1); ss += __shfl_xor(ss, 2);
        float inv = 1.f / fmaxf(sqrtf(ss), 1e-12f);
        if (l < 32)
            usu[(m >> 2) * 5 + (m & 3)] =
                make_uint2(pack_h2(a.x * inv, a.y * inv),
                           pack_h2(a.z * inv, a.w * inv));
    }
    wave_sync_lds();

    int my_amax = 0;
    for (int it = 1; it < ROUTIT; ++it) {
        // ---- p = z . u  (z from registers, u broadcast from LDS)
        float pr[4];
#pragma unroll
        for (int j = 0; j < 4; ++j) {
            float s = 0.f;
            const uint2* uk = &usu[(kh * 4 + j) * 5];
#pragma unroll
            for (int c2 = 0; c2 < 4; ++c2) {
                uint2 zz = zpr[j * 4 + c2];
                uint2 uu = uk[c2];
                s = __builtin_amdgcn_fdot2(ash2(zz.x), ash2(uu.x), s, false);
                s = __builtin_amdgcn_fdot2(ash2(zz.y), ash2(uu.y), s, false);
            }
            pr[j] = s;
        }
        if (LAST && it == ROUTIT - 1) {
            float po_[4];
#pragma unroll
            for (int j = 0; j < 4; ++j) po_[j] = __shfl_xor(pr[j], 32);
            float p8[8];
#pragma unroll
            for (int j = 0; j < 4; ++j) {
                p8[kh * 4 + j] = pr[j];
                p8[(kh ^ 1) * 4 + j] = po_[j];
            }
            float bv = p8[0]; int bi = 0;
#pragma unroll
            for (int k2 = 1; k2 < 8; ++k2)
                if (p8[k2] > bv) { bv = p8[k2]; bi = k2; }
            my_amax = bi;
            if (l < 32) amax[(size_t)v * M + m] = bi;
        }
        float er[4], S = 0.f;
#pragma unroll
        for (int j = 0; j < 4; ++j) { er[j] = __expf(pr[j]); S += er[j]; }
#pragma unroll
        for (int j = 0; j < 4; ++j) S += __shfl_xor(er[j], 32);
        float rS = 1.f / S;
        // producer: pack pk as f16 pairs (pk,0),(0,pk) once
#pragma unroll
        for (int j = 0; j < 4; ++j) {
            float pkv = er[j] * rS;
            pT2[(kh * 4 + j) * 36 + m] =
                make_uint2(pack_h2(pkv, 0.f), pack_h2(0.f, pkv));
        }
        wave_sync_lds();

        // ---- u update: a = sum_j z[row j][slot m] * p, pure fdot2
        float4 a = make_float4(0.f, 0.f, 0.f, 0.f);
        {
            const int k2 = m >> 2;
            const uint2* pb = &pT2[k2 * 36 + kh * 16];
#pragma unroll
            for (int j = 0; j < 16; ++j) {
                uint2 pq = pb[j];
                a.x = __builtin_amdgcn_fdot2(ash2(zu[j].x), ash2(pq.x), a.x, false);
                a.y = __builtin_amdgcn_fdot2(ash2(zu[j].x), ash2(pq.y), a.y, false);
                a.z = __builtin_amdgcn_fdot2(ash2(zu[j].y), ash2(pq.x), a.z, false);
                a.w = __builtin_amdgcn_fdot2(ash2(zu[j].y), ash2(pq.y), a.w, false);
            }
        }
        a.x += __shfl_xor(a.x, 32); a.y += __shfl_xor(a.y, 32);
        a.z += __shfl_xor(a.z, 32); a.w += __shfl_xor(a.w, 32);
        a.x += x3.x; a.y += x3.y; a.z += x3.z; a.w += x3.w;

        if (it < ROUTIT - 1) {
            float ss = a.x * a.x + a.y * a.y + a.z * a.z + a.w * a.w;
            ss += __shfl_xor(ss, 1); ss += __shfl_xor(ss, 2);
            float inv = 1.f / fmaxf(sqrtf(ss), 1e-12f);
            if (l < 32)
                usu[(m >> 2) * 5 + (m & 3)] =
                    make_uint2(pack_h2(a.x * inv, a.y * inv),
                               pack_h2(a.z * inv, a.w * inv));
            wave_sync_lds();
        } else if (LAST) {
            if (l < 32) ((float4*)(outF + (size_t)v * D))[m] = a;
            // ---- merged s2: sum first-5-neighbor selected capsules from
            // intact zsu rows 0..4 (z == those nodes' xc1 rows, row n = 0)
            int c = l & 15;
            float s = 0.f;
#pragma unroll
            for (int b = 0; b < CUT; ++b) {
                int jjb = __shfl(my_amax, b);        // argmax of row b (lane b)
                int slot = jjb * 4 + (c >> 2);
                uint2 zz = zsu[b * 32 + (slot ^ b)];
                unsigned word = (c & 2) ? zz.y : zz.x;
                h2 hh = ash2(word);
                s += (c & 1) ? (float)hh.y : (float)hh.x;
            }
            if (l < 16) s2out[(size_t)v * 16 + c] = s;
        } else {
            float r0 = fmaxf(a.x, 0.f), r1 = fmaxf(a.y, 0.f);
            float r2 = fmaxf(a.z, 0.f), r3 = fmaxf(a.w, 0.f);
            float ss = r0 * r0 + r1 * r1 + r2 * r2 + r3 * r3;
            ss += __shfl_xor(ss, 1); ss += __shfl_xor(ss, 2);
            float inv = 1.f / fmaxf(sqrtf(ss), 1e-12f);
            if (l < 32)
                *(uint2*)(outH + (size_t)v * 64 + m * 2) =
                    make_uint2(pack_h2(r0 * inv, r1 * inv),
                               pack_h2(r2 * inv, r3 * inv));
        }
    }
}

// ---------------------------------------------------------------- meta gather + MLP + log_softmax
// (R21: attn-loss partial sum merged in, block 0 wave 0)
__global__ __launch_bounds__(256) void meta_kernel(
        const float* __restrict__ u1, const float* __restrict__ s2,
        const int* __restrict__ nb, const int* __restrict__ amax,
        const float* __restrict__ mlp_w, const float* __restrict__ mlp_b,
        const float* __restrict__ partial, float* __restrict__ d_out,
        int n, int npart) {
    __shared__ float Wl[128 * 16];
    __shared__ float accs[16][132];
    const int t = threadIdx.x;
#pragma unroll
    for (int i = 0; i < 8; ++i) Wl[t + i * 256] = mlp_w[t + i * 256];
    const int g = t >> 4, c = t & 15;
    const int v = blockIdx.x * 16 + g;
    if (blockIdx.x == 0 && t < 64) {
        float s = 0.f;
        for (int i = t; i < npart; i += 64) s += partial[i];
        s += __shfl_xor(s, 1);  s += __shfl_xor(s, 2);
        s += __shfl_xor(s, 4);  s += __shfl_xor(s, 8);
        s += __shfl_xor(s, 16); s += __shfl_xor(s, 32);
        if (t == 0) d_out[(size_t)n * 16] = s * (1.f / (56.f * (float)n));
    }
    if (v < n) {
#pragma unroll
        for (int i = 0; i < 8; ++i) accs[g][i * 16 + c] = 0.f;
        for (int a = 0; a < CUT; ++a) {
            int w = nb[(size_t)v * M + a];
            if (w < 0) continue;
            int i = amax[(size_t)v * M + a];   // first-hop capsule
            accs[g][i * 16 + c] += s2[(size_t)w * 16 + c];
        }
#pragma unroll
        for (int i = 0; i < 8; ++i) {
            float meta = u1[(size_t)v * D + i * 16 + c] + accs[g][i * 16 + c] * (1.f / 25.f);
            accs[g][i * 16 + c] = fmaxf(meta, 0.f);
        }
    }
    __syncthreads();
    if (v < n) {
        float o = mlp_b[c];
#pragma unroll
        for (int dd = 0; dd < 128; ++dd) o += accs[g][dd] * Wl[dd * 16 + c];
        float mx = o;
        mx = fmaxf(mx, __shfl_xor(mx, 1));
        mx = fmaxf(mx, __shfl_xor(mx, 2));
        mx = fmaxf(mx, __shfl_xor(mx, 4));
        mx = fmaxf(mx, __shfl_xor(mx, 8));
        float e = __expf(o - mx);
        float se = wred16_sum(e);
        float ls = (o - mx) - logf(se);
        d_out[(size_t)v * 16 + c] = ls;
        d_out[(size_t)n * 16 + 1 + (size_t)v * 16 + c] = o;
    }
}

// ---------------------------------------------------------------- launch
extern "C" void kernel_launch(void* const* d_in, const int* in_sizes, int n_in,
                              void* d_out, int out_size, void* d_ws, size_t ws_size,
                              hipStream_t stream) {
    const float* x     = (const float*)d_in[0];
    const int*   nb    = (const int*)d_in[1];
    const float* pca_w = (const float*)d_in[2];
    const float* pca_b = (const float*)d_in[3];
    const float* ln_g  = (const float*)d_in[4];
    const float* ln_b  = (const float*)d_in[5];
    const float* w_qs  = (const float*)d_in[6];
    const float* w_ks  = (const float*)d_in[7];
    const float* mlp_w = (const float*)d_in[8];
    const float* mlp_b = (const float*)d_in[9];
    float* out = (float*)d_out;

    const int d = 128;
    const int nfeat = in_sizes[2] / d;      // 500
    const int n = in_sizes[0] / nfeat;      // 20000
    const int nblk = (n + 31) / 32;         // fused pca_attn blocks (625)

    float* bufA = (float*)d_ws;                           // n*128 f32 : u1
    unsigned* bufB = (unsigned*)(bufA + (size_t)n * d);   // (n+1)*64 : xc0 f16; later amax+s2
    unsigned* bufC = bufB + (size_t)(n + 1) * 64;         // (n+1)*64 : xc1 f16
    float* partial = (float*)(bufC + (size_t)(n + 1) * 64);  // nblk floats, dedicated
    int* amax = (int*)bufB;                               // n*32 ints (xc0 dead)
    float* s2 = (float*)((int*)bufB + (size_t)n * M);     // n*16 floats, after amax

    pca_attn<<<nblk, 256, 0, stream>>>(x, pca_w, pca_b, ln_g, ln_b, w_qs, w_ks,
                                       bufB, bufC, partial, n, nfeat);
    routing_kernel<false><<<n, 64, 0, stream>>>(bufB, nb, nullptr, bufC,
                                                nullptr, nullptr, n);
    routing_kernel<true><<<n, 64, 0, stream>>>(bufC, nb, bufA, nullptr,
                                               amax, s2, n);
    meta_kernel<<<(n + 15) / 16, 256, 0, stream>>>(bufA, s2, nb, amax, mlp_w,
                                                   mlp_b, partial, out, n, nblk);
}

// Round 12
// 234.399 us; speedup vs baseline: 1.0490x; 1.0469x over previous
//
#include <hip/hip_runtime.h>
#include <math.h>

#define NCAPS 8
#define DD    16
#define D     128
#define M     32
#define ROUTIT 6
#define CUT   5

__device__ __forceinline__ float wred16_sum(float v) {
    v += __shfl_xor(v, 1);
    v += __shfl_xor(v, 2);
    v += __shfl_xor(v, 4);
    v += __shfl_xor(v, 8);
    return v;
}

// per-wave "sync" (1-wave routing blocks): only LDS ordering needed.
__device__ __forceinline__ void wave_sync_lds() {
    asm volatile("s_waitcnt lgkmcnt(0)" ::: "memory");
}

// multi-wave barrier WITHOUT the compiler's vmcnt(0) drain.
__device__ __forceinline__ void bar_lgkm() {
    asm volatile("s_waitcnt lgkmcnt(0)" ::: "memory");
    __builtin_amdgcn_s_barrier();
    asm volatile("" ::: "memory");
}

// ---- f16 pair pack/unpack (RNE via default float->_Float16 conversion)
typedef _Float16 h2 __attribute__((ext_vector_type(2)));
union U32H2 { unsigned u; h2 h; };
__device__ __forceinline__ unsigned pack_h2(float a, float b) {
    U32H2 r; r.h.x = (_Float16)a; r.h.y = (_Float16)b; return r.u;
}
__device__ __forceinline__ h2 ash2(unsigned u) { U32H2 r; r.u = u; return r.h; }

// ---------------------------------------------------------------- fused PCA GEMM + attn loss + xc0
// (R20 structure: bar_lgkm barriers, merged dummy-row init)
__global__ __launch_bounds__(256) void pca_attn(
        const float* __restrict__ x, const float* __restrict__ w,
        const float* __restrict__ bias, const float* __restrict__ ln_g,
        const float* __restrict__ ln_b, const float* __restrict__ w_qs,
        const float* __restrict__ w_ks, unsigned* __restrict__ xc0H,
        unsigned* __restrict__ xc1H, float* __restrict__ partial,
        int n, int nfeat) {
    // union region: phase1 staging (xs2+ws2 = 6.6 KB) / phase3 ks (20.5 KB)
    __shared__ alignas(16) unsigned char uS[20480];
    unsigned (*xs2)[36]  = (unsigned(*)[36])uS;            // [kkp][row]
    unsigned (*ws2)[128] = (unsigned(*)[128])(uS + 1440);  // [kkp][col]
    float (*ks)[8][20]   = (float(*)[8][20])uS;            // [row][kq][c]
    __shared__ alignas(16) float hs[32][132];              // h tile, +4 pad
    __shared__ float wq[256], wk[256];
    __shared__ float red[4];
    const int tid = threadIdx.x;
    const int cg = tid & 31;
    const int rg = tid >> 5;
    const int row0 = blockIdx.x * 32;
    wq[tid] = w_qs[tid];
    wk[tid] = w_ks[tid];
    const float4 bi4 = *(const float4*)&bias[cg * 4];
    // merged init: dummy row n = 0 in both f16 xc buffers
    if (blockIdx.x == 0 && tid < 64) {
        xc0H[(size_t)n * 64 + tid] = 0u;
        xc1H[(size_t)n * 64 + tid] = 0u;
    }

    // ---- phase 1: f16-pair GEMM, 25 tiles of BK=20 (10 kk-pairs)
    const int xr_r = tid / 5, xr_cf = tid % 5;          // x-loader role (tid<160)
    const int wk0 = tid >> 5, wc0 = tid & 31;           // w task 0 (kkp 0..7)
    float4 xr{}, w0a{}, w0b{}, w1a{}, w1b{};

    // preload tile 0
    {
        if (tid < 160) {
            int row = row0 + xr_r;
            xr = (row < n) ? *(const float4*)&x[(size_t)row * nfeat + xr_cf * 4]
                           : make_float4(0.f, 0.f, 0.f, 0.f);
        }
        w0a = *(const float4*)&w[(size_t)(2 * wk0) * 128 + wc0 * 4];
        w0b = *(const float4*)&w[(size_t)(2 * wk0 + 1) * 128 + wc0 * 4];
        if (tid < 64) {
            int kkp = 8 + (tid >> 5);
            w1a = *(const float4*)&w[(size_t)(2 * kkp) * 128 + wc0 * 4];
            w1b = *(const float4*)&w[(size_t)(2 * kkp + 1) * 128 + wc0 * 4];
        }
    }
    float acc[4][4] = {};
    const int ntile = nfeat / 20;   // 25
    for (int t = 0; t < ntile; ++t) {
        bar_lgkm();   // previous tile's readers done (no vmem drain)
        if (tid < 160) {
            xs2[xr_cf * 2 + 0][xr_r] = pack_h2(xr.x, xr.y);
            xs2[xr_cf * 2 + 1][xr_r] = pack_h2(xr.z, xr.w);
        }
        {
            uint4 pw;
            pw.x = pack_h2(w0a.x, w0b.x); pw.y = pack_h2(w0a.y, w0b.y);
            pw.z = pack_h2(w0a.z, w0b.z); pw.w = pack_h2(w0a.w, w0b.w);
            *(uint4*)&ws2[wk0][wc0 * 4] = pw;
        }
        if (tid < 64) {
            int kkp = 8 + (tid >> 5);
            uint4 pw;
            pw.x = pack_h2(w1a.x, w1b.x); pw.y = pack_h2(w1a.y, w1b.y);
            pw.z = pack_h2(w1a.z, w1b.z); pw.w = pack_h2(w1a.w, w1b.w);
            *(uint4*)&ws2[kkp][wc0 * 4] = pw;
        }
        // issue next tile's loads -- stay in flight through barrier + compute
        if (t < ntile - 1) {
            int k0 = (t + 1) * 20;
            if (tid < 160) {
                int row = row0 + xr_r;
                xr = (row < n)
                    ? *(const float4*)&x[(size_t)row * nfeat + k0 + xr_cf * 4]
                    : make_float4(0.f, 0.f, 0.f, 0.f);
            }
            w0a = *(const float4*)&w[(size_t)(k0 + 2 * wk0) * 128 + wc0 * 4];
            w0b = *(const float4*)&w[(size_t)(k0 + 2 * wk0 + 1) * 128 + wc0 * 4];
            if (tid < 64) {
                int kkp = 8 + (tid >> 5);
                w1a = *(const float4*)&w[(size_t)(k0 + 2 * kkp) * 128 + wc0 * 4];
                w1b = *(const float4*)&w[(size_t)(k0 + 2 * kkp + 1) * 128 + wc0 * 4];
            }
        }
        bar_lgkm();   // LDS tile visible to all waves (no vmem drain)
#pragma unroll
        for (int kkp = 0; kkp < 10; ++kkp) {
            uint4 av = *(const uint4*)&xs2[kkp][rg * 4];   // 4 rows (broadcast)
            uint4 bv = *(const uint4*)&ws2[kkp][cg * 4];   // 4 cols
            unsigned aa[4] = {av.x, av.y, av.z, av.w};
            unsigned bb[4] = {bv.x, bv.y, bv.z, bv.w};
#pragma unroll
            for (int i = 0; i < 4; ++i)
#pragma unroll
                for (int j = 0; j < 4; ++j)
                    acc[i][j] = __builtin_amdgcn_fdot2(ash2(aa[i]), ash2(bb[j]),
                                                       acc[i][j], false);
        }
    }
#pragma unroll
    for (int i = 0; i < 4; ++i)
        *(float4*)&hs[rg * 4 + i][cg * 4] =
            make_float4(acc[i][0] + bi4.x, acc[i][1] + bi4.y,
                        acc[i][2] + bi4.z, acc[i][3] + bi4.w);
    bar_lgkm();   // hs ready; staging buffers dead -> ks may reuse

    // ---- phase 2: per-(row, capsule) LN + q/kk matmuls + xc0
    const int r = tid >> 3, kq = tid & 7;
    const int row = row0 + r;
    float hv[16], q[16], kk[16];
    if (row < n) {
#pragma unroll
        for (int i = 0; i < 4; ++i) {
            float4 f = *(const float4*)&hs[r][kq * 16 + i * 4];
            hv[i * 4 + 0] = f.x; hv[i * 4 + 1] = f.y;
            hv[i * 4 + 2] = f.z; hv[i * 4 + 3] = f.w;
        }
        float mu = 0.f;
#pragma unroll
        for (int c = 0; c < 16; ++c) mu += hv[c];
        mu *= (1.f / 16.f);
        float var = 0.f;
#pragma unroll
        for (int c = 0; c < 16; ++c) { float d = hv[c] - mu; var += d * d; }
        var *= (1.f / 16.f);
        float rstd = rsqrtf(var + 1e-6f);
        float qn[16];
#pragma unroll
        for (int c = 0; c < 16; ++c)
            qn[c] = (hv[c] - mu) * rstd * ln_g[c] + ln_b[c];
#pragma unroll
        for (int c = 0; c < 16; ++c) { q[c] = 0.f; kk[c] = 0.f; }
#pragma unroll
        for (int cp = 0; cp < 16; ++cp)
#pragma unroll
            for (int c = 0; c < 16; ++c) {
                q[c]  += qn[cp] * wq[cp * 16 + c];
                kk[c] += hv[cp] * wk[cp * 16 + c];
            }
#pragma unroll
        for (int c = 0; c < 16; ++c) q[c] *= 0.25f;   // 1/sqrt(16)
#pragma unroll
        for (int i = 0; i < 4; ++i)
            *(float4*)&ks[r][kq][i * 4] =
                make_float4(kk[i * 4], kk[i * 4 + 1], kk[i * 4 + 2], kk[i * 4 + 3]);
        float ss = 0.f;
        float rl[16];
#pragma unroll
        for (int c = 0; c < 16; ++c) { rl[c] = fmaxf(hv[c], 0.f); ss += rl[c] * rl[c]; }
        float inv = 1.f / fmaxf(sqrtf(ss), 1e-12f);
        unsigned* xo = xc0H + (size_t)row * 64 + kq * 8;
        uint4 pa, pb;
        pa.x = pack_h2(rl[0] * inv,  rl[1] * inv);
        pa.y = pack_h2(rl[2] * inv,  rl[3] * inv);
        pa.z = pack_h2(rl[4] * inv,  rl[5] * inv);
        pa.w = pack_h2(rl[6] * inv,  rl[7] * inv);
        pb.x = pack_h2(rl[8] * inv,  rl[9] * inv);
        pb.y = pack_h2(rl[10] * inv, rl[11] * inv);
        pb.z = pack_h2(rl[12] * inv, rl[13] * inv);
        pb.w = pack_h2(rl[14] * inv, rl[15] * inv);
        *(uint4*)&xo[0] = pa;
        *(uint4*)&xo[4] = pb;
    }
    bar_lgkm();

    // ---- phase 3: scores row kq vs all 8 keys; softmax; off-diag sum
    float offd = 0.f;
    if (row < n) {
        float s[8];
#pragma unroll
        for (int j = 0; j < 8; ++j) {
            float d = 0.f;
#pragma unroll
            for (int i = 0; i < 4; ++i) {
                float4 f = *(const float4*)&ks[r][j][i * 4];
                d += q[i * 4] * f.x + q[i * 4 + 1] * f.y
                   + q[i * 4 + 2] * f.z + q[i * 4 + 3] * f.w;
            }
            s[j] = d;
        }
        float mx = s[0];
#pragma unroll
        for (int j = 1; j < 8; ++j) mx = fmaxf(mx, s[j]);
        float e[8], se = 0.f;
#pragma unroll
        for (int j = 0; j < 8; ++j) { e[j] = __expf(s[j] - mx); se += e[j]; }
        float rse = 1.f / se;
#pragma unroll
        for (int j = 0; j < 8; ++j)
            if (j != kq) offd += e[j] * rse;
    }
    offd += __shfl_xor(offd, 1);
    offd += __shfl_xor(offd, 2);
    offd += __shfl_xor(offd, 4);
    offd += __shfl_xor(offd, 8);
    offd += __shfl_xor(offd, 16);
    offd += __shfl_xor(offd, 32);
    int lane = tid & 63, wid = tid >> 6;
    if (lane == 0) red[wid] = offd;
    bar_lgkm();
    if (tid == 0) partial[blockIdx.x] = red[0] + red[1] + red[2] + red[3];
}

// ---------------------------------------------------------------- routing: ONE WAVE PER NODE
// R24 = R21 routing (f32 pT + vectorized float4 pk gather + cvt update --
// the best-measured form) plus R23's two DS-neutral VALU cuts:
//  - init-u via fdot2 with constant (1,0)/(0,1) h2 operands (kills 64 cvt)
//  - denominator via shfl of exp(pr) (bit-identical, kills 4 v_exp/iter)
// R23's pT2 f16-pair store is REVERTED: it turned 4 ds_read_b128 into 16
// ds_read_b64 per iteration and regressed. usu/pT alias zsu rows 26..31;
// rows 0..4 survive for the merged s2 epilogue.
template <bool LAST>
__global__ __launch_bounds__(64, 4) void routing_kernel(
        const unsigned* __restrict__ xcH, // (n+1)*64 f16-pairs, row n = 0
        const int* __restrict__ nb,       // n*32
        float* __restrict__ outF,         // LAST: u1 rows [0,n)
        unsigned* __restrict__ outH,      // !LAST: xc_next f16 rows [0,n)
        int* __restrict__ amax,           // LAST: n*32 argmax
        float* __restrict__ s2out,        // LAST: n*16 second-hop presum
        int n) {
    __shared__ alignas(16) unsigned char sbuf[8192];
    uint2* zsu = (uint2*)sbuf;            // [M*32] f16x4 staging slots
    uint2* usu = (uint2*)(sbuf + 6656);   // [40]   aliases zsu rows 26..27
    float* pT  = (float*)(sbuf + 6976);   // [8*36] aliases zsu rows ~27..31
    const int l = threadIdx.x;
    const int v = blockIdx.x;
    const int m  = l & 31;   // also f4 (dd-slot index in update phase)
    const int kh = l >> 5;   // also mg (row-half index in update phase)
    const unsigned ONE_LO = 0x00003C00u;  // h2(1,0)
    const unsigned ONE_HI = 0x3C000000u;  // h2(0,1)

    // ---- stage 32 neighbor rows -> LDS (XOR-swizzled slots), f16 direct
    float4 x3;
    {
        int sm = l >> 1, sh = l & 1;
        int src = 0;
        if (l < M) {
            int nbv = nb[(size_t)v * M + l];
            src = (nbv < 0) ? n : nbv;
        }
        int srow = __shfl(src, sm);
        const uint4* g = (const uint4*)(xcH + (size_t)srow * 64 + sh * 32);
        uint2 xv = *(const uint2*)(xcH + (size_t)v * 64 + m * 2);
        uint4 zb[8];
#pragma unroll
        for (int i = 0; i < 8; ++i) zb[i] = g[i];      // all 8 loads in flight
        {
            h2 xlo = ash2(xv.x), xhi = ash2(xv.y);
            x3 = make_float4((float)xlo.x, (float)xlo.y,
                             (float)xhi.x, (float)xhi.y);
        }
#pragma unroll
        for (int i = 0; i < 8; ++i) {
            int f0 = sh * 16 + 2 * i;
            zsu[sm * 32 + (f0 ^ sm)]       = make_uint2(zb[i].x, zb[i].y);
            zsu[sm * 32 + ((f0 + 1) ^ sm)] = make_uint2(zb[i].z, zb[i].w);
        }
    }
    wave_sync_lds();

    // ---- one-time register hoist of both z access patterns (forced: the
    // usu/pT writes below may alias zsu, so these cannot be rematerialized)
    uint2 zpr[16];
#pragma unroll
    for (int idx = 0; idx < 16; ++idx) {
        int f = kh * 16 + idx;
        zpr[idx] = zsu[m * 32 + (f ^ m)];
    }
    uint2 zu[16];
#pragma unroll
    for (int j = 0; j < 16; ++j) {
        int r = kh * 16 + j;
        zu[j] = zsu[r * 32 + (m ^ r)];
    }
    wave_sync_lds();   // all hoist reads done before usu/pT clobber rows 26..31

    // ---- initial u: mean over 32 neighbor rows (p = 1/8 uniform) + x3
    {
        float4 a = make_float4(0.f, 0.f, 0.f, 0.f);
#pragma unroll
        for (int j = 0; j < 16; ++j) {
            a.x = __builtin_amdgcn_fdot2(ash2(zu[j].x), ash2(ONE_LO), a.x, false);
            a.y = __builtin_amdgcn_fdot2(ash2(zu[j].x), ash2(ONE_HI), a.y, false);
            a.z = __builtin_amdgcn_fdot2(ash2(zu[j].y), ash2(ONE_LO), a.z, false);
            a.w = __builtin_amdgcn_fdot2(ash2(zu[j].y), ash2(ONE_HI), a.w, false);
        }
        a.x += __shfl_xor(a.x, 32); a.y += __shfl_xor(a.y, 32);
        a.z += __shfl_xor(a.z, 32); a.w += __shfl_xor(a.w, 32);
        a.x = a.x * 0.125f + x3.x;  a.y = a.y * 0.125f + x3.y;
        a.z = a.z * 0.125f + x3.z;  a.w = a.w * 0.125f + x3.w;
        float ss = a.x * a.x + a.y * a.y + a.z * a.z + a.w * a.w;
        ss += __shfl_xor(ss, 1); ss += __shfl_xor(ss, 2);
        float inv = 1.f / fmaxf(sqrtf(ss), 1e-12f);
        if (l < 32)
            usu[(m >> 2) * 5 + (m & 3)] =
                make_uint2(pack_h2(a.x * inv, a.y * inv),
                           pack_h2(a.z * inv, a.w * inv));
    }
    wave_sync_lds();

    int my_amax = 0;
    for (int it = 1; it < ROUTIT; ++it) {
        // ---- p = z . u  (z from registers, u broadcast from LDS)
        float pr[4];
#pragma unroll
        for (int j = 0; j < 4; ++j) {
            float s = 0.f;
            const uint2* uk = &usu[(kh * 4 + j) * 5];
#pragma unroll
            for (int c2 = 0; c2 < 4; ++c2) {
                uint2 zz = zpr[j * 4 + c2];
                uint2 uu = uk[c2];
                s = __builtin_amdgcn_fdot2(ash2(zz.x), ash2(uu.x), s, false);
                s = __builtin_amdgcn_fdot2(ash2(zz.y), ash2(uu.y), s, false);
            }
            pr[j] = s;
        }
        if (LAST && it == ROUTIT - 1) {
            float po_[4];
#pragma unroll
            for (int j = 0; j < 4; ++j) po_[j] = __shfl_xor(pr[j], 32);
            float p8[8];
#pragma unroll
            for (int j = 0; j < 4; ++j) {
                p8[kh * 4 + j] = pr[j];
                p8[(kh ^ 1) * 4 + j] = po_[j];
            }
            float bv = p8[0]; int bi = 0;
#pragma unroll
            for (int k2 = 1; k2 < 8; ++k2)
                if (p8[k2] > bv) { bv = p8[k2]; bi = k2; }
            my_amax = bi;
            if (l < 32) amax[(size_t)v * M + m] = bi;
        }
        float er[4], S = 0.f;
#pragma unroll
        for (int j = 0; j < 4; ++j) { er[j] = __expf(pr[j]); S += er[j]; }
#pragma unroll
        for (int j = 0; j < 4; ++j) S += __shfl_xor(er[j], 32);
        float rS = 1.f / S;
#pragma unroll
        for (int j = 0; j < 4; ++j)
            pT[(kh * 4 + j) * 36 + m] = er[j] * rS;
        wave_sync_lds();

        // ---- gather p for this lane's (capsule, row-half)
        float pk[16];
        {
            const int k2 = m >> 2;
#pragma unroll
            for (int j4 = 0; j4 < 4; ++j4) {
                float4 pp = *(const float4*)&pT[k2 * 36 + kh * 16 + j4 * 4];
                pk[j4 * 4 + 0] = pp.x; pk[j4 * 4 + 1] = pp.y;
                pk[j4 * 4 + 2] = pp.z; pk[j4 * 4 + 3] = pp.w;
            }
        }
        // ---- u update: a = sum_j z[row j][slot m] * p  (z from registers)
        float4 a = make_float4(0.f, 0.f, 0.f, 0.f);
#pragma unroll
        for (int j = 0; j < 16; ++j) {
            h2 lo = ash2(zu[j].x), hi = ash2(zu[j].y);
            a.x += (float)lo.x * pk[j]; a.y += (float)lo.y * pk[j];
            a.z += (float)hi.x * pk[j]; a.w += (float)hi.y * pk[j];
        }
        a.x += __shfl_xor(a.x, 32); a.y += __shfl_xor(a.y, 32);
        a.z += __shfl_xor(a.z, 32); a.w += __shfl_xor(a.w, 32);
        a.x += x3.x; a.y += x3.y; a.z += x3.z; a.w += x3.w;

        if (it < ROUTIT - 1) {
            float ss = a.x * a.x + a.y * a.y + a.z * a.z + a.w * a.w;
            ss += __shfl_xor(ss, 1); ss += __shfl_xor(ss, 2);
            float inv = 1.f / fmaxf(sqrtf(ss), 1e-12f);
            if (l < 32)
                usu[(m >> 2) * 5 + (m & 3)] =
                    make_uint2(pack_h2(a.x * inv, a.y * inv),
                               pack_h2(a.z * inv, a.w * inv));
            wave_sync_lds();
        } else if (LAST) {
            if (l < 32) ((float4*)(outF + (size_t)v * D))[m] = a;
            // ---- merged s2: sum first-5-neighbor selected capsules from
            // intact zsu rows 0..4 (z == those nodes' xc1 rows, row n = 0)
            int c = l & 15;
            float s = 0.f;
#pragma unroll
            for (int b = 0; b < CUT; ++b) {
                int jjb = __shfl(my_amax, b);        // argmax of row b (lane b)
                int slot = jjb * 4 + (c >> 2);
                uint2 zz = zsu[b * 32 + (slot ^ b)];
                unsigned word = (c & 2) ? zz.y : zz.x;
                h2 hh = ash2(word);
                s += (c & 1) ? (float)hh.y : (float)hh.x;
            }
            if (l < 16) s2out[(size_t)v * 16 + c] = s;
        } else {
            float r0 = fmaxf(a.x, 0.f), r1 = fmaxf(a.y, 0.f);
            float r2 = fmaxf(a.z, 0.f), r3 = fmaxf(a.w, 0.f);
            float ss = r0 * r0 + r1 * r1 + r2 * r2 + r3 * r3;
            ss += __shfl_xor(ss, 1); ss += __shfl_xor(ss, 2);
            float inv = 1.f / fmaxf(sqrtf(ss), 1e-12f);
            if (l < 32)
                *(uint2*)(outH + (size_t)v * 64 + m * 2) =
                    make_uint2(pack_h2(r0 * inv, r1 * inv),
                               pack_h2(r2 * inv, r3 * inv));
        }
    }
}

// ---------------------------------------------------------------- meta gather + MLP + log_softmax
// (R21: attn-loss partial sum merged in, block 0 wave 0)
__global__ __launch_bounds__(256) void meta_kernel(
        const float* __restrict__ u1, const float* __restrict__ s2,
        const int* __restrict__ nb, const int* __restrict__ amax,
        const float* __restrict__ mlp_w, const float* __restrict__ mlp_b,
        const float* __restrict__ partial, float* __restrict__ d_out,
        int n, int npart) {
    __shared__ float Wl[128 * 16];
    __shared__ float accs[16][132];
    const int t = threadIdx.x;
#pragma unroll
    for (int i = 0; i < 8; ++i) Wl[t + i * 256] = mlp_w[t + i * 256];
    const int g = t >> 4, c = t & 15;
    const int v = blockIdx.x * 16 + g;
    if (blockIdx.x == 0 && t < 64) {
        float s = 0.f;
        for (int i = t; i < npart; i += 64) s += partial[i];
        s += __shfl_xor(s, 1);  s += __shfl_xor(s, 2);
        s += __shfl_xor(s, 4);  s += __shfl_xor(s, 8);
        s += __shfl_xor(s, 16); s += __shfl_xor(s, 32);
        if (t == 0) d_out[(size_t)n * 16] = s * (1.f / (56.f * (float)n));
    }
    if (v < n) {
#pragma unroll
        for (int i = 0; i < 8; ++i) accs[g][i * 16 + c] = 0.f;
        for (int a = 0; a < CUT; ++a) {
            int w = nb[(size_t)v * M + a];
            if (w < 0) continue;
            int i = amax[(size_t)v * M + a];   // first-hop capsule
            accs[g][i * 16 + c] += s2[(size_t)w * 16 + c];
        }
#pragma unroll
        for (int i = 0; i < 8; ++i) {
            float meta = u1[(size_t)v * D + i * 16 + c] + accs[g][i * 16 + c] * (1.f / 25.f);
            accs[g][i * 16 + c] = fmaxf(meta, 0.f);
        }
    }
    __syncthreads();
    if (v < n) {
        float o = mlp_b[c];
#pragma unroll
        for (int dd = 0; dd < 128; ++dd) o += accs[g][dd] * Wl[dd * 16 + c];
        float mx = o;
        mx = fmaxf(mx, __shfl_xor(mx, 1));
        mx = fmaxf(mx, __shfl_xor(mx, 2));
        mx = fmaxf(mx, __shfl_xor(mx, 4));
        mx = fmaxf(mx, __shfl_xor(mx, 8));
        float e = __expf(o - mx);
        float se = wred16_sum(e);
        float ls = (o - mx) - logf(se);
        d_out[(size_t)v * 16 + c] = ls;
        d_out[(size_t)n * 16 + 1 + (size_t)v * 16 + c] = o;
    }
}

// ---------------------------------------------------------------- launch
extern "C" void kernel_launch(void* const* d_in, const int* in_sizes, int n_in,
                              void* d_out, int out_size, void* d_ws, size_t ws_size,
                              hipStream_t stream) {
    const float* x     = (const float*)d_in[0];
    const int*   nb    = (const int*)d_in[1];
    const float* pca_w = (const float*)d_in[2];
    const float* pca_b = (const float*)d_in[3];
    const float* ln_g  = (const float*)d_in[4];
    const float* ln_b  = (const float*)d_in[5];
    const float* w_qs  = (const float*)d_in[6];
    const float* w_ks  = (const float*)d_in[7];
    const float* mlp_w = (const float*)d_in[8];
    const float* mlp_b = (const float*)d_in[9];
    float* out = (float*)d_out;

    const int d = 128;
    const int nfeat = in_sizes[2] / d;      // 500
    const int n = in_sizes[0] / nfeat;      // 20000
    const int nblk = (n + 31) / 32;         // fused pca_attn blocks (625)

    float* bufA = (float*)d_ws;                           // n*128 f32 : u1
    unsigned* bufB = (unsigned*)(bufA + (size_t)n * d);   // (n+1)*64 : xc0 f16; later amax+s2
    unsigned* bufC = bufB + (size_t)(n + 1) * 64;         // (n+1)*64 : xc1 f16
    float* partial = (float*)(bufC + (size_t)(n + 1) * 64);  // nblk floats, dedicated
    int* amax = (int*)bufB;                               // n*32 ints (xc0 dead)
    float* s2 = (float*)((int*)bufB + (size_t)n * M);     // n*16 floats, after amax

    pca_attn<<<nblk, 256, 0, stream>>>(x, pca_w, pca_b, ln_g, ln_b, w_qs, w_ks,
                                       bufB, bufC, partial, n, nfeat);
    routing_kernel<false><<<n, 64, 0, stream>>>(bufB, nb, nullptr, bufC,
                                                nullptr, nullptr, n);
    routing_kernel<true><<<n, 64, 0, stream>>>(bufC, nb, bufA, nullptr,
                                               amax, s2, n);
    meta_kernel<<<(n + 15) / 16, 256, 0, stream>>>(bufA, s2, nb, amax, mlp_w,
                                                   mlp_b, partial, out, n, nblk);
}